// Round 2
// baseline (1341.561 us; speedup 1.0000x reference)
//
#include <hip/hip_runtime.h>
#include <stdint.h>

typedef unsigned short u16;
typedef unsigned int u32;

// ---------- bf16 helpers ----------
__device__ __forceinline__ float bf2f(u16 u){
  union { u32 i; float f; } v; v.i = ((u32)u) << 16; return v.f;
}
__device__ __forceinline__ u16 f2bf(float f){
  union { float f; u32 i; } v; v.f = f;
  u32 i = v.i;
  return (u16)((i + 0x7fffu + ((i >> 16) & 1u)) >> 16); // RNE
}
__device__ __forceinline__ float sgnf(float w){
  return (w > 0.f) ? 1.f : ((w < 0.f) ? -1.f : 0.f);
}

// ---------- block reduction (256 threads = 4 waves) ----------
__device__ __forceinline__ void block_reduce2(float& a, float& b){
  #pragma unroll
  for (int off = 32; off > 0; off >>= 1){
    a += __shfl_down(a, off);
    b += __shfl_down(b, off);
  }
  __shared__ float ra[4], rb[4];
  int lane = threadIdx.x & 63, w = threadIdx.x >> 6;
  __syncthreads();
  if (lane == 0){ ra[w] = a; rb[w] = b; }
  __syncthreads();
  if (threadIdx.x == 0){
    a = ra[0] + ra[1] + ra[2] + ra[3];
    b = rb[0] + rb[1] + rb[2] + rb[3];
  }
}

// ---------- zero small ws region ----------
__global__ void k_zero(float* __restrict__ p, int n){
  int i = blockIdx.x * blockDim.x + threadIdx.x;
  if (i < n) p[i] = 0.f;
}

// ---------- sum(|w|) for the 4 weight tensors (all fp32) ----------
__global__ __launch_bounds__(256) void k_absum(const float* __restrict__ w1, const float* __restrict__ w2,
                                               const float* __restrict__ wfc1, const float* __restrict__ wfc2,
                                               float* __restrict__ absum){
  int b = blockIdx.x, t = threadIdx.x;
  const float* src; int n0, cnt, slot;
  if (b < 64)      { src = wfc1; slot = 2; cnt = 2097152/64; n0 = b * cnt; }
  else if (b < 96) { src = w2;   slot = 1; cnt = 73728/32;   n0 = (b-64) * cnt; }
  else if (b == 96){ src = w1;   slot = 0; cnt = 1728;       n0 = 0; }
  else             { src = wfc2; slot = 3; cnt = 2560;       n0 = 0; }
  float s = 0.f, d = 0.f;
  for (int i = t; i < cnt; i += 256) s += fabsf(src[n0 + i]);
  block_reduce2(s, d);
  if (t == 0) atomicAdd(absum + slot, s);
}

// ---------- materialize sign weights (fp32, conv ones transposed to [k][co]) ----------
__global__ __launch_bounds__(256) void k_sign(const float* __restrict__ w1, const float* __restrict__ w2,
                                              const float* __restrict__ wfc2,
                                              float* __restrict__ qw1t, float* __restrict__ qw2t,
                                              float* __restrict__ qwfc2){
  int i = blockIdx.x * 256 + threadIdx.x;
  if (i < 1728){
    int co = i / 27, k = i % 27;
    qw1t[k*64 + co] = sgnf(w1[i]);
  } else if (i < 1728 + 73728){
    int j = i - 1728;
    int co = j / 576, k = j % 576;
    qw2t[k*128 + co] = sgnf(w2[j]);
  } else if (i < 1728 + 73728 + 2560){
    int j = i - 75456;
    qwfc2[j] = sgnf(wfc2[j]);
  }
}

// ---------- conv1: x[1024,3,32,32] fp32 -> h1[1024,64,32,32] bf16 (scaled by alpha1) ----------
__global__ __launch_bounds__(256) void k_conv1(const float* __restrict__ x, const float* __restrict__ qw1t,
                                               const float* __restrict__ absum, u16* __restrict__ h1){
  __shared__ float xs[3*34*36]; // [ci][y 0..33][x 0..35], data at y=1..32, x=2..33
  int n = blockIdx.x, t = threadIdx.x;
  for (int i = t; i < 3672; i += 256) xs[i] = 0.f;
  __syncthreads();
  const float4* xg = (const float4*)(x + (size_t)n * 3072);
  for (int i = t; i < 768; i += 256){
    float4 v = xg[i];
    int ci = i >> 8, rem = i & 255, y = rem >> 3, xq = (rem & 7) * 4;
    int base = ci*1224 + (y+1)*36 + 2 + xq;
    xs[base+0] = v.x; xs[base+1] = v.y; xs[base+2] = v.z; xs[base+3] = v.w;
  }
  __syncthreads();
  float alpha = absum[0] * (1.f/1728.f);
  int yy0[4], xx0[4];
  #pragma unroll
  for (int s = 0; s < 4; ++s){ int sp = t + 256*s; yy0[s] = sp >> 5; xx0[s] = sp & 31; }
  for (int cc = 0; cc < 8; ++cc){
    float acc[4][8];
    #pragma unroll
    for (int s = 0; s < 4; ++s)
      #pragma unroll
      for (int r = 0; r < 8; ++r) acc[s][r] = 0.f;
    for (int ci = 0; ci < 3; ++ci){
      #pragma unroll
      for (int dy = 0; dy < 3; ++dy){
        #pragma unroll
        for (int dx = 0; dx < 3; ++dx){
          int k = ci*9 + dy*3 + dx;
          float wv[8];
          #pragma unroll
          for (int r = 0; r < 8; ++r) wv[r] = qw1t[k*64 + cc*8 + r]; // uniform -> s_load
          #pragma unroll
          for (int s = 0; s < 4; ++s){
            float a = xs[ci*1224 + (yy0[s]+dy)*36 + (xx0[s]+dx+1)];
            #pragma unroll
            for (int r = 0; r < 8; ++r) acc[s][r] += a * wv[r];
          }
        }
      }
    }
    #pragma unroll
    for (int r = 0; r < 8; ++r){
      size_t base = ((size_t)n*64 + cc*8 + r) * 1024;
      #pragma unroll
      for (int s = 0; s < 4; ++s) h1[base + t + 256*s] = f2bf(acc[s][r] * alpha);
    }
  }
}

// ---------- per-channel sum/sumsq over bf16 [1024][C][plane] ----------
__global__ __launch_bounds__(256) void k_stats(const u16* __restrict__ src, float* __restrict__ sum,
                                               float* __restrict__ sumsq, int C, int plane){
  int c = blockIdx.x, s = blockIdx.y, t = threadIdx.x;
  int nsplit = gridDim.y;
  float s1 = 0.f, s2 = 0.f;
  int pd = plane >> 1;
  for (int n = s; n < 1024; n += nsplit){
    const u32* pu = (const u32*)(src + ((size_t)n*C + c) * plane);
    for (int i = t; i < pd; i += 256){
      u32 v = pu[i];
      float a = bf2f((u16)(v & 0xffffu)), b = bf2f((u16)(v >> 16));
      s1 += a + b; s2 += a*a + b*b;
    }
  }
  block_reduce2(s1, s2);
  if (t == 0){ atomicAdd(sum + c, s1); atomicAdd(sumsq + c, s2); }
}

// ---------- finalize BN affine params (g,b fp32) ----------
__global__ void k_fin(const float* __restrict__ sum, const float* __restrict__ sumsq,
                      const float* __restrict__ g, const float* __restrict__ b,
                      float* __restrict__ scale, float* __restrict__ bias, int C, float invc){
  int c = blockIdx.x * blockDim.x + threadIdx.x;
  if (c >= C) return;
  float m = sum[c] * invc;
  float var = sumsq[c] * invc - m*m;
  float sc = g[c] * rsqrtf(var + 1e-5f);
  scale[c] = sc;
  bias[c] = b[c] - m * sc;
}

// ---------- BN + ReLU + 2x2 maxpool (bf16 -> bf16) ----------
template<int C, int HW> // HW = output spatial dim
__global__ __launch_bounds__(256) void k_pool(const u16* __restrict__ src, u16* __restrict__ dst,
                                              const float* __restrict__ scale, const float* __restrict__ bias){
  int idx = blockIdx.x * 256 + threadIdx.x;
  int x = idx % HW;
  int y = (idx / HW) % HW;
  int c = (idx / (HW*HW)) % C;
  int n = idx / (HW*HW*C);
  const u32* pu = (const u32*)(src + ((size_t)(n*C + c)*2*HW + 2*y) * (2*HW));
  u32 va = pu[x], vb = pu[x + HW];
  float sc = scale[c], bi = bias[c];
  float v0 = bf2f((u16)(va & 0xffffu)) * sc + bi;
  float v1 = bf2f((u16)(va >> 16))     * sc + bi;
  float v2 = bf2f((u16)(vb & 0xffffu)) * sc + bi;
  float v3 = bf2f((u16)(vb >> 16))     * sc + bi;
  float m = fmaxf(fmaxf(v0, v1), fmaxf(v2, v3));
  dst[idx] = f2bf(fmaxf(m, 0.f));
}

// ---------- conv2: p1[1024,64,16,16] bf16 -> h2[1024,128,16,16] bf16 ----------
__global__ __launch_bounds__(256) void k_conv2(const u16* __restrict__ p1, const float* __restrict__ qw2t,
                                               const float* __restrict__ absum, u16* __restrict__ h2){
  __shared__ u16 ps[64*18*20]; // [ci][y 0..17][x 0..19], data y=1..16, x=2..17 (dword aligned)
  int n = blockIdx.x, t = threadIdx.x;
  u32* psu = (u32*)ps;
  for (int i = t; i < 11520; i += 256) psu[i] = 0u;
  __syncthreads();
  const u32* pg = (const u32*)(p1 + (size_t)n * 16384);
  for (int r = t; r < 1024; r += 256){
    int c = r >> 4, y = r & 15;
    int dst = c*180 + (y+1)*10 + 1; // dword index
    int sd = r * 8;
    #pragma unroll
    for (int q = 0; q < 8; ++q) psu[dst + q] = pg[sd + q];
  }
  __syncthreads();
  float alpha = absum[1] * (1.f/73728.f);
  int yy = t >> 4, xx = t & 15;
  for (int cc = 0; cc < 4; ++cc){
    float acc[32];
    #pragma unroll
    for (int r = 0; r < 32; ++r) acc[r] = 0.f;
    for (int ci = 0; ci < 64; ++ci){
      #pragma unroll
      for (int dy = 0; dy < 3; ++dy){
        #pragma unroll
        for (int dx = 0; dx < 3; ++dx){
          float a = bf2f(ps[ci*360 + (yy+dy)*20 + (xx+dx+1)]);
          const float* wr = qw2t + ((ci*9 + dy*3 + dx)*128 + cc*32); // uniform -> s_load
          #pragma unroll
          for (int r = 0; r < 32; ++r) acc[r] += a * wr[r];
        }
      }
    }
    size_t base = ((size_t)n*128 + cc*32) * 256 + t;
    #pragma unroll
    for (int r = 0; r < 32; ++r) h2[base + (size_t)r*256] = f2bf(acc[r] * alpha);
  }
}

// ---------- fc1: p2[1024,8192] bf16 @ sign(wfc1[256,8192] fp32)^T -> h3 fp32 [1024,256] ----------
__global__ __launch_bounds__(256) void k_fc1(const u16* __restrict__ p2, const float* __restrict__ wfc1,
                                             const float* __restrict__ absum, float* __restrict__ h3){
  __shared__ float As[32*66]; // [m][k], row stride 66 (2-way bank alias only)
  __shared__ float Bs[32*66]; // [j][k] sign values
  int t = threadIdx.x;
  int bm = blockIdx.x, bn = blockIdx.y;
  int ty = t >> 4, tx = t & 15;
  float c00 = 0.f, c01 = 0.f, c10 = 0.f, c11 = 0.f;
  const u32* Ag = (const u32*)p2;
  for (int k0 = 0; k0 < 8192; k0 += 64){
    // A: 32 rows x 64 k (bf16 source, 32 dwords/row) -> 1024 dwords, 4/thread
    #pragma unroll
    for (int i = 0; i < 4; ++i){
      int di = t + 256*i;
      int m = di >> 5, kp = di & 31;
      u32 va = Ag[(size_t)(bm*32 + m)*4096 + (k0 >> 1) + kp];
      As[m*66 + kp*2]     = bf2f((u16)(va & 0xffffu));
      As[m*66 + kp*2 + 1] = bf2f((u16)(va >> 16));
    }
    // B: 32 rows x 64 k fp32 -> 512 float4, 2/thread
    #pragma unroll
    for (int i = 0; i < 2; ++i){
      int di = t + 256*i;
      int m = di >> 4, kq = (di & 15) * 4;
      float4 v = *(const float4*)(wfc1 + (size_t)(bn*32 + m)*8192 + k0 + kq);
      Bs[m*66 + kq]     = sgnf(v.x);
      Bs[m*66 + kq + 1] = sgnf(v.y);
      Bs[m*66 + kq + 2] = sgnf(v.z);
      Bs[m*66 + kq + 3] = sgnf(v.w);
    }
    __syncthreads();
    #pragma unroll 4
    for (int kk = 0; kk < 64; ++kk){
      float a0 = As[(ty*2)*66 + kk];
      float a1 = As[(ty*2+1)*66 + kk];
      float b0 = Bs[(tx*2)*66 + kk];
      float b1 = Bs[(tx*2+1)*66 + kk];
      c00 += a0*b0; c01 += a0*b1; c10 += a1*b0; c11 += a1*b1;
    }
    __syncthreads();
  }
  float alpha = absum[2] * (1.f/2097152.f);
  int m0 = bm*32 + ty*2, j0 = bn*32 + tx*2;
  h3[(size_t)m0*256 + j0]         = c00 * alpha;
  h3[(size_t)m0*256 + j0 + 1]     = c01 * alpha;
  h3[(size_t)(m0+1)*256 + j0]     = c10 * alpha;
  h3[(size_t)(m0+1)*256 + j0 + 1] = c11 * alpha;
}

// ---------- BN3 stats+finalize: one block per feature (g,b fp32) ----------
__global__ __launch_bounds__(256) void k_fin3(const float* __restrict__ h3, const float* __restrict__ g,
                                              const float* __restrict__ b, float* __restrict__ scale,
                                              float* __restrict__ bias){
  int j = blockIdx.x, t = threadIdx.x;
  float s1 = 0.f, s2 = 0.f;
  for (int n = t; n < 1024; n += 256){
    float v = h3[(size_t)n*256 + j];
    s1 += v; s2 += v*v;
  }
  block_reduce2(s1, s2);
  if (t == 0){
    float m = s1 * (1.f/1024.f);
    float var = s2 * (1.f/1024.f) - m*m;
    float sc = g[j] * rsqrtf(var + 1e-5f);
    scale[j] = sc;
    bias[j] = b[j] - m*sc;
  }
}

// ---------- fc2: relu(bn3(h3)) @ sign(wfc2)^T -> out[1024,10] fp32 ----------
__global__ __launch_bounds__(64) void k_fc2(const float* __restrict__ h3, const float* __restrict__ qwfc2,
                                            const float* __restrict__ absum, const float* __restrict__ scale,
                                            const float* __restrict__ bias, float* __restrict__ out){
  int n = blockIdx.x, lane = threadIdx.x;
  float a[4];
  #pragma unroll
  for (int i = 0; i < 4; ++i){
    int j = lane + 64*i;
    float v = h3[(size_t)n*256 + j] * scale[j] + bias[j];
    a[i] = fmaxf(v, 0.f);
  }
  float alpha = absum[3] * (1.f/2560.f);
  #pragma unroll
  for (int k = 0; k < 10; ++k){
    float p = 0.f;
    #pragma unroll
    for (int i = 0; i < 4; ++i) p += a[i] * qwfc2[k*256 + lane + 64*i];
    #pragma unroll
    for (int off = 32; off > 0; off >>= 1) p += __shfl_down(p, off);
    if (lane == 0) out[n*10 + k] = p * alpha;
  }
}

extern "C" void kernel_launch(void* const* d_in, const int* in_sizes, int n_in,
                              void* d_out, int out_size, void* d_ws, size_t ws_size,
                              hipStream_t stream){
  (void)in_sizes; (void)n_in; (void)out_size; (void)ws_size;
  const float* x    = (const float*)d_in[0];
  const float* w1   = (const float*)d_in[1];
  const float* g1   = (const float*)d_in[2];
  const float* b1   = (const float*)d_in[3];
  const float* w2   = (const float*)d_in[4];
  const float* g2   = (const float*)d_in[5];
  const float* b2   = (const float*)d_in[6];
  const float* wfc1 = (const float*)d_in[7];
  const float* g3   = (const float*)d_in[8];
  const float* b3   = (const float*)d_in[9];
  const float* wfc2 = (const float*)d_in[10];
  float* out = (float*)d_out;

  float* wsf = (float*)d_ws;
  char*  wsb = (char*)d_ws;
  float* absum = wsf + 0;                 // 4
  float* s1 = wsf + 16;   float* q1 = wsf + 80;    // 64 each
  float* s2 = wsf + 144;  float* q2 = wsf + 272;   // 128 each
  float* sc1 = wsf + 1024; float* bi1 = wsf + 1088;
  float* sc2 = wsf + 1152; float* bi2 = wsf + 1280;
  float* sc3 = wsf + 1408; float* bi3 = wsf + 1664;
  float* qw1t  = wsf + 4096;              // 1728 fp32  [27][64]
  float* qw2t  = wsf + 8192;              // 73728 fp32 [576][128]
  float* qwfc2 = wsf + 81920;             // 2560 fp32  [10][256]
  float* h3    = wsf + 262144;            // 1 MB fp32  [1024][256]
  u16* h1 = (u16*)(wsb + ((size_t)16 << 20));   // 128 MB bf16
  u16* p1 = (u16*)(wsb + ((size_t)144 << 20));  // 32 MB bf16
  u16* h2 = h1;                                  // alias (h1 dead after pool1)
  u16* p2 = p1;                                  // alias (p1 dead after conv2)

  k_zero<<<8, 256, 0, stream>>>(wsf, 2048);
  k_absum<<<98, 256, 0, stream>>>(w1, w2, wfc1, wfc2, absum);
  k_sign<<<305, 256, 0, stream>>>(w1, w2, wfc2, qw1t, qw2t, qwfc2);
  k_conv1<<<1024, 256, 0, stream>>>(x, qw1t, absum, h1);
  k_stats<<<dim3(64, 32), 256, 0, stream>>>(h1, s1, q1, 64, 1024);
  k_fin<<<1, 64, 0, stream>>>(s1, q1, g1, b1, sc1, bi1, 64, 1.f/1048576.f);
  k_pool<64,16><<<65536, 256, 0, stream>>>(h1, p1, sc1, bi1);
  k_conv2<<<1024, 256, 0, stream>>>(p1, qw2t, absum, h2);
  k_stats<<<dim3(128, 32), 256, 0, stream>>>(h2, s2, q2, 128, 256);
  k_fin<<<1, 128, 0, stream>>>(s2, q2, g2, b2, sc2, bi2, 128, 1.f/262144.f);
  k_pool<128,8><<<32768, 256, 0, stream>>>(h2, p2, sc2, bi2);
  k_fc1<<<dim3(32, 8), 256, 0, stream>>>(p2, wfc1, absum, h3);
  k_fin3<<<256, 256, 0, stream>>>(h3, g3, b3, sc3, bi3);
  k_fc2<<<1024, 64, 0, stream>>>(h3, qwfc2, absum, sc3, bi3, out);
}

// Round 3
// 669.602 us; speedup vs baseline: 2.0035x; 2.0035x over previous
//
#include <hip/hip_runtime.h>
#include <stdint.h>

typedef unsigned short u16;
typedef unsigned int u32;
typedef __attribute__((ext_vector_type(8))) short s8v;   // 8 bf16 = 4 VGPR (MFMA A/B frag)
typedef __attribute__((ext_vector_type(4))) float f4v;   // MFMA C/D frag
typedef __attribute__((ext_vector_type(8))) u16 u16x8;
typedef __attribute__((ext_vector_type(4))) u16 u16x4;

// ---------- bf16 helpers ----------
__device__ __forceinline__ float bf2f(u16 u){
  union { u32 i; float f; } v; v.i = ((u32)u) << 16; return v.f;
}
__device__ __forceinline__ u16 f2bf(float f){
  union { float f; u32 i; } v; v.f = f;
  u32 i = v.i;
  return (u16)((i + 0x7fffu + ((i >> 16) & 1u)) >> 16); // RNE
}
__device__ __forceinline__ float sgnf(float w){
  return (w > 0.f) ? 1.f : ((w < 0.f) ? -1.f : 0.f);
}
__device__ __forceinline__ u16 sgn_bf(float w){
  return (w > 0.f) ? (u16)0x3F80 : ((w < 0.f) ? (u16)0xBF80 : (u16)0);
}

// ---------- block reduction (256 threads = 4 waves) ----------
__device__ __forceinline__ void block_reduce2(float& a, float& b){
  #pragma unroll
  for (int off = 32; off > 0; off >>= 1){
    a += __shfl_down(a, off);
    b += __shfl_down(b, off);
  }
  __shared__ float ra[4], rb[4];
  int lane = threadIdx.x & 63, w = threadIdx.x >> 6;
  __syncthreads();
  if (lane == 0){ ra[w] = a; rb[w] = b; }
  __syncthreads();
  if (threadIdx.x == 0){
    a = ra[0] + ra[1] + ra[2] + ra[3];
    b = rb[0] + rb[1] + rb[2] + rb[3];
  }
}

__global__ void k_zero(float* __restrict__ p, int n){
  int i = blockIdx.x * blockDim.x + threadIdx.x;
  if (i < n) p[i] = 0.f;
}

// ---------- sum(|w|) for the 4 weight tensors ----------
__global__ __launch_bounds__(256) void k_absum(const float* __restrict__ w1, const float* __restrict__ w2,
                                               const float* __restrict__ wfc1, const float* __restrict__ wfc2,
                                               float* __restrict__ absum){
  int b = blockIdx.x, t = threadIdx.x;
  const float* src; int n0, cnt, slot;
  if (b < 64)      { src = wfc1; slot = 2; cnt = 2097152/64; n0 = b * cnt; }
  else if (b < 96) { src = w2;   slot = 1; cnt = 73728/32;   n0 = (b-64) * cnt; }
  else if (b == 96){ src = w1;   slot = 0; cnt = 1728;       n0 = 0; }
  else             { src = wfc2; slot = 3; cnt = 2560;       n0 = 0; }
  float s = 0.f, d = 0.f;
  for (int i = t; i < cnt; i += 256) s += fabsf(src[n0 + i]);
  block_reduce2(s, d);
  if (t == 0) atomicAdd(absum + slot, s);
}

// ---------- generate all quantized weight forms ----------
// qw1t: fp32 [27 k][64 co] for conv1 VALU
// qw2b: bf16 MFMA B-frags, frag_id = (s*2+ks)*8+nt, u16 idx = frag*512 + lane*8 + j
//       value = sign(w2[co=nt*16+(lane&15)][c=ks*32+(lane>>4)*8+j][dy][dx]), s=dy*3+dx
// qfc1b: bf16 MFMA B-frags, frag = kstep*16+nt, value = sign(wfc1[co][k=kstep*32+(lane>>4)*8+j])
// qwfc2: fp32 sign [10][256]
__global__ __launch_bounds__(256) void k_signgen(const float* __restrict__ w1, const float* __restrict__ w2,
                                                 const float* __restrict__ wfc1, const float* __restrict__ wfc2,
                                                 float* __restrict__ qw1t, u16* __restrict__ qw2b,
                                                 u16* __restrict__ qfc1b, float* __restrict__ qwfc2){
  int i = blockIdx.x * 256 + threadIdx.x;
  if (i < 2097152){
    int j = i & 7, lane = (i >> 3) & 63, fid = i >> 9;
    int kstep = fid >> 4, nt = fid & 15;
    int co = nt*16 + (lane & 15);
    int k = kstep*32 + (lane >> 4)*8 + j;
    qfc1b[i] = sgn_bf(wfc1[(size_t)co*8192 + k]);
  } else if (i < 2097152 + 73728){
    int i2 = i - 2097152;
    int j = i2 & 7, lane = (i2 >> 3) & 63, fid = i2 >> 9;  // 0..143
    int s = fid >> 4, ks = (fid >> 3) & 1, nt = fid & 7;
    int co = nt*16 + (lane & 15);
    int c = ks*32 + (lane >> 4)*8 + j;
    qw2b[i2] = sgn_bf(w2[((size_t)co*64 + c)*9 + s]);
  } else if (i < 2097152 + 73728 + 1728){
    int i3 = i - (2097152 + 73728);
    int co = i3 / 27, k = i3 % 27;
    qw1t[k*64 + co] = sgnf(w1[i3]);
  } else if (i < 2097152 + 73728 + 1728 + 2560){
    int i4 = i - (2097152 + 73728 + 1728);
    qwfc2[i4] = sgnf(wfc2[i4]);
  }
}

// ---------- conv1: x[1024,3,32,32] fp32 -> h1t[1024, 1024px, 64c] bf16 channel-last ----------
__global__ __launch_bounds__(256) void k_conv1(const float* __restrict__ x, const float* __restrict__ qw1t,
                                               const float* __restrict__ absum, u16* __restrict__ h1t){
  __shared__ float xs[3*34*36]; // [ci][y 0..33][x 0..35], data y=1..32, x=2..33
  int n = blockIdx.x, t = threadIdx.x;
  for (int i = t; i < 3672; i += 256) xs[i] = 0.f;
  __syncthreads();
  const float4* xg = (const float4*)(x + (size_t)n * 3072);
  for (int i = t; i < 768; i += 256){
    float4 v = xg[i];
    int ci = i >> 8, rem = i & 255, y = rem >> 3, xq = (rem & 7) * 4;
    int base = ci*1224 + (y+1)*36 + 2 + xq;
    xs[base+0] = v.x; xs[base+1] = v.y; xs[base+2] = v.z; xs[base+3] = v.w;
  }
  __syncthreads();
  float alpha = absum[0] * (1.f/1728.f);
  int yy0[4], xx0[4];
  #pragma unroll
  for (int s = 0; s < 4; ++s){ int sp = t + 256*s; yy0[s] = sp >> 5; xx0[s] = sp & 31; }
  for (int cc = 0; cc < 8; ++cc){
    float acc[4][8];
    #pragma unroll
    for (int s = 0; s < 4; ++s)
      #pragma unroll
      for (int r = 0; r < 8; ++r) acc[s][r] = 0.f;
    for (int ci = 0; ci < 3; ++ci){
      #pragma unroll
      for (int dy = 0; dy < 3; ++dy){
        #pragma unroll
        for (int dx = 0; dx < 3; ++dx){
          int k = ci*9 + dy*3 + dx;
          float wv[8];
          #pragma unroll
          for (int r = 0; r < 8; ++r) wv[r] = qw1t[k*64 + cc*8 + r]; // uniform -> s_load
          #pragma unroll
          for (int s = 0; s < 4; ++s){
            float a = xs[ci*1224 + (yy0[s]+dy)*36 + (xx0[s]+dx+1)];
            #pragma unroll
            for (int r = 0; r < 8; ++r) acc[s][r] += a * wv[r];
          }
        }
      }
    }
    #pragma unroll
    for (int s = 0; s < 4; ++s){
      u16x8 pk;
      #pragma unroll
      for (int r = 0; r < 8; ++r) pk[r] = f2bf(acc[s][r] * alpha);
      *(u16x8*)(h1t + ((size_t)n*1024 + t + 256*s)*64 + cc*8) = pk;
    }
  }
}

// ---------- per-channel stats over channel-last h1t[1024][1024][64] ----------
__global__ __launch_bounds__(256) void k_stats_cl(const u16* __restrict__ h1t, float* __restrict__ sum,
                                                  float* __restrict__ sumsq){
  int n = blockIdx.x, t = threadIdx.x;
  int cp = t & 31, chunk = t >> 5;
  const u32* base = (const u32*)h1t + (size_t)n * 32768;
  float s1a = 0.f, s2a = 0.f, s1b = 0.f, s2b = 0.f;
  for (int px = chunk; px < 1024; px += 8){
    u32 v = base[px*32 + cp];
    float a = bf2f((u16)(v & 0xffffu)), b = bf2f((u16)(v >> 16));
    s1a += a; s2a += a*a; s1b += b; s2b += b*b;
  }
  __shared__ float l1[256], l2[256], l3[256], l4[256];
  l1[t] = s1a; l2[t] = s2a; l3[t] = s1b; l4[t] = s2b;
  __syncthreads();
  if (t < 32){
    float a = 0.f, b = 0.f, c = 0.f, d = 0.f;
    #pragma unroll
    for (int k = 0; k < 8; ++k){ a += l1[t+32*k]; b += l2[t+32*k]; c += l3[t+32*k]; d += l4[t+32*k]; }
    atomicAdd(sum + 2*t, a);     atomicAdd(sumsq + 2*t, b);
    atomicAdd(sum + 2*t + 1, c); atomicAdd(sumsq + 2*t + 1, d);
  }
}

// ---------- finalize BN affine params ----------
__global__ void k_fin(const float* __restrict__ sum, const float* __restrict__ sumsq,
                      const float* __restrict__ g, const float* __restrict__ b,
                      float* __restrict__ scale, float* __restrict__ bias, int C, float invc){
  int c = blockIdx.x * blockDim.x + threadIdx.x;
  if (c >= C) return;
  float m = sum[c] * invc;
  float var = sumsq[c] * invc - m*m;
  float sc = g[c] * rsqrtf(var + 1e-5f);
  scale[c] = sc;
  bias[c] = b[c] - m * sc;
}

// ---------- BN+ReLU+pool on channel-last, h1t[1024][32x32][64] -> p1t[1024][16x16][64] ----------
// note: scale>0 (g=1), so max-then-affine == affine-then-max (exact)
__global__ __launch_bounds__(256) void k_pool1t(const u16* __restrict__ h1t, u16* __restrict__ p1t,
                                                const float* __restrict__ sc, const float* __restrict__ bi){
  __shared__ float lsc[64], lbi[64];
  int n = blockIdx.x, t = threadIdx.x;
  if (t < 64) lsc[t] = sc[t];
  else if (t < 128) lbi[t - 64] = bi[t - 64];
  __syncthreads();
  int oy = t >> 4, ox = t & 15;
  const u16* b00 = h1t + ((size_t)n*1024 + oy*64 + ox*2)*64;
  u16x8 ovv[8];
  #pragma unroll
  for (int v = 0; v < 8; ++v){
    u16x8 a0 = *(const u16x8*)(b00 + v*8);
    u16x8 a1 = *(const u16x8*)(b00 + 64 + v*8);
    u16x8 a2 = *(const u16x8*)(b00 + 2048 + v*8);
    u16x8 a3 = *(const u16x8*)(b00 + 2112 + v*8);
    #pragma unroll
    for (int j = 0; j < 8; ++j){
      int c = v*8 + j;
      float m = fmaxf(fmaxf(bf2f(a0[j]), bf2f(a1[j])), fmaxf(bf2f(a2[j]), bf2f(a3[j])));
      ovv[v][j] = f2bf(fmaxf(m * lsc[c] + lbi[c], 0.f));
    }
  }
  u16* dst = p1t + ((size_t)n*256 + t)*64;
  #pragma unroll
  for (int v = 0; v < 8; ++v) *(u16x8*)(dst + v*8) = ovv[v];
}

// ---------- conv2 via MFMA implicit GEMM + fused BN2 stats ----------
// p1t[1024][256px][64c] bf16 -> h2[1024][128co][16][16] bf16 (scaled by alpha2)
// per block: one image; M=256 px, N=128 co, K=576 (9 shifts x 64 ch)
// wave w: mh=w>>1 (y rows mh*8..+7), nh=w&1 (co half)
__global__ __launch_bounds__(256, 2) void k_conv2m(const u16* __restrict__ p1t, const u16* __restrict__ qw2b,
                                                   const float* __restrict__ absum, u16* __restrict__ h2,
                                                   float* __restrict__ gs, float* __restrict__ gq){
  __shared__ u16 bsh[8192];      // 16 KB: B frags for current shift
  __shared__ float ls1[128], ls2[128];
  int n = blockIdx.x, t = threadIdx.x;
  if (t < 128){ ls1[t] = 0.f; ls2[t] = 0.f; }
  int w = t >> 6, lane = t & 63;
  int l15 = lane & 15, q = lane >> 4;
  int mh = w >> 1, nh = w & 1;
  const s8v* bp = (const s8v*)qw2b;
  s8v* bs = (s8v*)bsh;
  const u16* img = p1t + (size_t)n * 16384;
  f4v acc[8][4];
  #pragma unroll
  for (int a = 0; a < 8; ++a)
    #pragma unroll
    for (int b = 0; b < 4; ++b) acc[a][b] = (f4v)(0.0f);
  for (int dy = 0; dy < 3; ++dy){
    for (int dx = 0; dx < 3; ++dx){
      int s = dy*3 + dx;
      __syncthreads();
      #pragma unroll
      for (int i = 0; i < 4; ++i) bs[t + 256*i] = bp[s*1024 + t + 256*i];
      __syncthreads();
      int xv = l15 + dx - 1;
      bool vx = (xv >= 0) && (xv < 16);
      #pragma unroll
      for (int ks = 0; ks < 2; ++ks){
        s8v bf[4];
        #pragma unroll
        for (int nt = 0; nt < 4; ++nt) bf[nt] = bs[(ks*8 + nh*4 + nt)*64 + lane];
        #pragma unroll
        for (int mt = 0; mt < 8; ++mt){
          int yv = mh*8 + mt + dy - 1;
          if (yv < 0 || yv > 15) continue;
          s8v av = *(const s8v*)(img + (yv*16 + xv)*64 + ks*32 + q*8);
          if (!vx) av = (s8v)(short)0;
          #pragma unroll
          for (int nt = 0; nt < 4; ++nt)
            acc[mt][nt] = __builtin_amdgcn_mfma_f32_16x16x32_bf16(av, bf[nt], acc[mt][nt], 0, 0, 0);
        }
      }
    }
  }
  float alpha = absum[1] * (1.f/73728.f);
  #pragma unroll
  for (int mt = 0; mt < 8; ++mt){
    int y = mh*8 + mt;
    #pragma unroll
    for (int nt = 0; nt < 4; ++nt){
      int co = nh*64 + nt*16 + l15;
      float v0 = acc[mt][nt][0] * alpha;
      float v1 = acc[mt][nt][1] * alpha;
      float v2 = acc[mt][nt][2] * alpha;
      float v3 = acc[mt][nt][3] * alpha;
      atomicAdd(&ls1[co], v0 + v1 + v2 + v3);
      atomicAdd(&ls2[co], v0*v0 + v1*v1 + v2*v2 + v3*v3);
      u16x4 pk; pk[0] = f2bf(v0); pk[1] = f2bf(v1); pk[2] = f2bf(v2); pk[3] = f2bf(v3);
      *(u16x4*)(h2 + ((size_t)(n*128 + co)*16 + y)*16 + q*4) = pk;
    }
  }
  __syncthreads();
  if (t < 128){ atomicAdd(gs + t, ls1[t]); atomicAdd(gq + t, ls2[t]); }
}

// ---------- BN + ReLU + 2x2 maxpool (standard layout, for conv2 output) ----------
template<int C, int HW>
__global__ __launch_bounds__(256) void k_pool(const u16* __restrict__ src, u16* __restrict__ dst,
                                              const float* __restrict__ scale, const float* __restrict__ bias){
  int idx = blockIdx.x * 256 + threadIdx.x;
  int x = idx % HW;
  int y = (idx / HW) % HW;
  int c = (idx / (HW*HW)) % C;
  int n = idx / (HW*HW*C);
  const u32* pu = (const u32*)(src + ((size_t)(n*C + c)*2*HW + 2*y) * (2*HW));
  u32 va = pu[x], vb = pu[x + HW];
  float sc = scale[c], bi = bias[c];
  float v0 = bf2f((u16)(va & 0xffffu)) * sc + bi;
  float v1 = bf2f((u16)(va >> 16))     * sc + bi;
  float v2 = bf2f((u16)(vb & 0xffffu)) * sc + bi;
  float v3 = bf2f((u16)(vb >> 16))     * sc + bi;
  float m = fmaxf(fmaxf(v0, v1), fmaxf(v2, v3));
  dst[idx] = f2bf(fmaxf(m, 0.f));
}

// ---------- fc1 via MFMA with k-split: p2[1024][8192] bf16 x signs -> h3p[32][1024][256] fp32 ----------
__global__ __launch_bounds__(256) void k_fc1m(const u16* __restrict__ p2, const u16* __restrict__ qfc1b,
                                              const float* __restrict__ absum, float* __restrict__ h3p){
  int t = threadIdx.x;
  int bm = blockIdx.x, bn = blockIdx.y, kb = blockIdx.z;
  int w = t >> 6, lane = t & 63, l15 = lane & 15, q = lane >> 4;
  int rowbase = bm*128 + (w >> 1)*64;
  int ntb = bn*8 + (w & 1)*4;
  const s8v* bp = (const s8v*)qfc1b;
  f4v acc[4][4];
  #pragma unroll
  for (int a = 0; a < 4; ++a)
    #pragma unroll
    for (int b = 0; b < 4; ++b) acc[a][b] = (f4v)(0.0f);
  for (int ks = 0; ks < 8; ++ks){
    int kst = kb*8 + ks;
    s8v bf[4], af[4];
    #pragma unroll
    for (int nt = 0; nt < 4; ++nt) bf[nt] = bp[(kst*16 + ntb + nt)*64 + lane];
    #pragma unroll
    for (int mt = 0; mt < 4; ++mt)
      af[mt] = *(const s8v*)(p2 + (size_t)(rowbase + mt*16 + l15)*8192 + kst*32 + q*8);
    #pragma unroll
    for (int mt = 0; mt < 4; ++mt)
      #pragma unroll
      for (int nt = 0; nt < 4; ++nt)
        acc[mt][nt] = __builtin_amdgcn_mfma_f32_16x16x32_bf16(af[mt], bf[nt], acc[mt][nt], 0, 0, 0);
  }
  float alpha = absum[2] * (1.f/2097152.f);
  float* dst = h3p + (size_t)kb * 262144;
  #pragma unroll
  for (int mt = 0; mt < 4; ++mt)
    #pragma unroll
    for (int nt = 0; nt < 4; ++nt){
      int col = (ntb + nt)*16 + l15;
      #pragma unroll
      for (int r = 0; r < 4; ++r)
        dst[(size_t)(rowbase + mt*16 + q*4 + r)*256 + col] = acc[mt][nt][r] * alpha;
    }
}

// ---------- reduce k-split slabs + BN3 stats + materialize h3 ----------
__global__ __launch_bounds__(256) void k_fin3f(const float* __restrict__ h3p, float* __restrict__ h3,
                                               float* __restrict__ s3, float* __restrict__ q3){
  int jb = blockIdx.x, ns = blockIdx.y, t = threadIdx.x;
  int jj = t & 31, nn = t >> 5;
  int j = jb*32 + jj;
  float s1 = 0.f, s2 = 0.f;
  for (int i = nn; i < 128; i += 8){
    int n = i*8 + ns;
    float v = 0.f;
    #pragma unroll 8
    for (int kb = 0; kb < 32; ++kb) v += h3p[(size_t)kb*262144 + n*256 + j];
    h3[n*256 + j] = v;
    s1 += v; s2 += v*v;
  }
  __shared__ float l1[256], l2[256];
  l1[t] = s1; l2[t] = s2;
  __syncthreads();
  if (t < 32){
    float a = 0.f, b = 0.f;
    #pragma unroll
    for (int k = 0; k < 8; ++k){ a += l1[t+32*k]; b += l2[t+32*k]; }
    atomicAdd(s3 + jb*32 + t, a); atomicAdd(q3 + jb*32 + t, b);
  }
}

// ---------- fc2: relu(bn3(h3)) @ sign(wfc2)^T -> out[1024,10] fp32 ----------
__global__ __launch_bounds__(64) void k_fc2(const float* __restrict__ h3, const float* __restrict__ qwfc2,
                                            const float* __restrict__ absum, const float* __restrict__ scale,
                                            const float* __restrict__ bias, float* __restrict__ out){
  int n = blockIdx.x, lane = threadIdx.x;
  float a[4];
  #pragma unroll
  for (int i = 0; i < 4; ++i){
    int j = lane + 64*i;
    float v = h3[(size_t)n*256 + j] * scale[j] + bias[j];
    a[i] = fmaxf(v, 0.f);
  }
  float alpha = absum[3] * (1.f/2560.f);
  #pragma unroll
  for (int k = 0; k < 10; ++k){
    float p = 0.f;
    #pragma unroll
    for (int i = 0; i < 4; ++i) p += a[i] * qwfc2[k*256 + lane + 64*i];
    #pragma unroll
    for (int off = 32; off > 0; off >>= 1) p += __shfl_down(p, off);
    if (lane == 0) out[n*10 + k] = p * alpha;
  }
}

extern "C" void kernel_launch(void* const* d_in, const int* in_sizes, int n_in,
                              void* d_out, int out_size, void* d_ws, size_t ws_size,
                              hipStream_t stream){
  (void)in_sizes; (void)n_in; (void)out_size; (void)ws_size;
  const float* x    = (const float*)d_in[0];
  const float* w1   = (const float*)d_in[1];
  const float* g1   = (const float*)d_in[2];
  const float* b1   = (const float*)d_in[3];
  const float* w2   = (const float*)d_in[4];
  const float* g2   = (const float*)d_in[5];
  const float* b2   = (const float*)d_in[6];
  const float* wfc1 = (const float*)d_in[7];
  const float* g3   = (const float*)d_in[8];
  const float* b3   = (const float*)d_in[9];
  const float* wfc2 = (const float*)d_in[10];
  float* out = (float*)d_out;

  float* wsf = (float*)d_ws;
  char*  wsb = (char*)d_ws;
  float* absum = wsf;
  float* s1 = wsf + 16;   float* q1 = wsf + 80;
  float* s2 = wsf + 144;  float* q2 = wsf + 272;
  float* s3 = wsf + 1024; float* q3 = wsf + 1280;
  float* sc1 = wsf + 1536; float* bi1 = wsf + 1600;
  float* sc2 = wsf + 1664; float* bi2 = wsf + 1792;
  float* sc3 = wsf + 2048; float* bi3 = wsf + 2304;
  float* qw1t  = wsf + 4096;                         // 1728 fp32
  u16*   qw2b  = (u16*)(wsb + (64u << 10));          // 144 KB bf16 B-frags
  float* qwfc2 = (float*)(wsb + (256u << 10));       // 10 KB fp32
  float* h3    = (float*)(wsb + (1ull << 20));       // 1 MB fp32 [1024][256]
  u16*   qfc1b = (u16*)(wsb + (2ull << 20));         // 4 MB bf16 B-frags
  u16*   p1t   = (u16*)(wsb + (8ull << 20) + 4096);  // 32 MB bf16 [1024][256][64] (+guards)
  u16*   h1t   = (u16*)(wsb + (48ull << 20));        // 128 MB bf16 [1024][1024][64]
  u16*   h2    = h1t;                                // 64 MB alias (h1t dead after pool1t)
  u16*   p2    = (u16*)(wsb + (112ull << 20));       // 16 MB bf16 [1024][8192]
  float* h3p   = (float*)(wsb + (48ull << 20));      // 32 MB fp32 [32][1024][256] (h2 dead)

  k_zero<<<10, 256, 0, stream>>>(wsf, 2560);
  k_absum<<<98, 256, 0, stream>>>(w1, w2, wfc1, wfc2, absum);
  k_signgen<<<8498, 256, 0, stream>>>(w1, w2, wfc1, wfc2, qw1t, qw2b, qfc1b, qwfc2);
  k_conv1<<<1024, 256, 0, stream>>>(x, qw1t, absum, h1t);
  k_stats_cl<<<1024, 256, 0, stream>>>(h1t, s1, q1);
  k_fin<<<1, 64, 0, stream>>>(s1, q1, g1, b1, sc1, bi1, 64, 1.f/1048576.f);
  k_pool1t<<<1024, 256, 0, stream>>>(h1t, p1t, sc1, bi1);
  k_conv2m<<<1024, 256, 0, stream>>>(p1t, qw2b, absum, h2, s2, q2);
  k_fin<<<1, 128, 0, stream>>>(s2, q2, g2, b2, sc2, bi2, 128, 1.f/262144.f);
  k_pool<128, 8><<<32768, 256, 0, stream>>>(h2, p2, sc2, bi2);
  k_fc1m<<<dim3(8, 2, 32), 256, 0, stream>>>(p2, qfc1b, absum, h3p);
  k_fin3f<<<dim3(8, 8), 256, 0, stream>>>(h3p, h3, s3, q3);
  k_fin<<<1, 256, 0, stream>>>(s3, q3, g3, b3, sc3, bi3, 256, 1.f/1024.f);
  k_fc2<<<1024, 64, 0, stream>>>(h3, qwfc2, absum, sc3, bi3, out);
}

// Round 4
// 573.703 us; speedup vs baseline: 2.3384x; 1.1672x over previous
//
#include <hip/hip_runtime.h>
#include <stdint.h>

typedef unsigned short u16;
typedef unsigned int u32;
typedef __attribute__((ext_vector_type(8))) short s8v;   // 8 bf16 = 4 VGPR (MFMA A/B frag)
typedef __attribute__((ext_vector_type(4))) float f4v;   // MFMA C/D frag
typedef __attribute__((ext_vector_type(8))) u16 u16x8;

// ---------- bf16 helpers ----------
__device__ __forceinline__ float bf2f(u16 u){
  union { u32 i; float f; } v; v.i = ((u32)u) << 16; return v.f;
}
__device__ __forceinline__ u16 f2bf(float f){
  union { float f; u32 i; } v; v.f = f;
  u32 i = v.i;
  return (u16)((i + 0x7fffu + ((i >> 16) & 1u)) >> 16); // RNE
}
__device__ __forceinline__ float sgnf(float w){
  return (w > 0.f) ? 1.f : ((w < 0.f) ? -1.f : 0.f);
}
__device__ __forceinline__ u16 sgn_bf(float w){
  return (w > 0.f) ? (u16)0x3F80 : ((w < 0.f) ? (u16)0xBF80 : (u16)0);
}

// ---------- block reduction (256 threads = 4 waves) ----------
__device__ __forceinline__ void block_reduce2(float& a, float& b){
  #pragma unroll
  for (int off = 32; off > 0; off >>= 1){
    a += __shfl_down(a, off);
    b += __shfl_down(b, off);
  }
  __shared__ float ra[4], rb[4];
  int lane = threadIdx.x & 63, w = threadIdx.x >> 6;
  __syncthreads();
  if (lane == 0){ ra[w] = a; rb[w] = b; }
  __syncthreads();
  if (threadIdx.x == 0){
    a = ra[0] + ra[1] + ra[2] + ra[3];
    b = rb[0] + rb[1] + rb[2] + rb[3];
  }
}

__global__ void k_zero(float* __restrict__ p, int n){
  int i = blockIdx.x * blockDim.x + threadIdx.x;
  if (i < n) p[i] = 0.f;
}

// ---------- sum(|w|) for the 4 weight tensors ----------
__global__ __launch_bounds__(256) void k_absum(const float* __restrict__ w1, const float* __restrict__ w2,
                                               const float* __restrict__ wfc1, const float* __restrict__ wfc2,
                                               float* __restrict__ absum){
  int b = blockIdx.x, t = threadIdx.x;
  const float* src; int n0, cnt, slot;
  if (b < 64)      { src = wfc1; slot = 2; cnt = 2097152/64; n0 = b * cnt; }
  else if (b < 96) { src = w2;   slot = 1; cnt = 73728/32;   n0 = (b-64) * cnt; }
  else if (b == 96){ src = w1;   slot = 0; cnt = 1728;       n0 = 0; }
  else             { src = wfc2; slot = 3; cnt = 2560;       n0 = 0; }
  float s = 0.f, d = 0.f;
  for (int i = t; i < cnt; i += 256) s += fabsf(src[n0 + i]);
  block_reduce2(s, d);
  if (t == 0) atomicAdd(absum + slot, s);
}

// ---------- generate all quantized weight forms ----------
// qw1t: fp32 [27 k][64 co] for conv1 VALU
// qw2b: bf16 MFMA B-frags for conv2, frag fid=(s*2+ks)*8+nt, elem idx=fid*512+lane*8+j
//       co = (lane&15)*8 + nt   (co permutation -> coalesced channel-last stores)
//       c  = ks*32 + (lane>>4)*8 + j
// qfc1b: bf16 MFMA B-frags for fc1, frag = kstep*16+nt; k_phys = kstep*32+(lane>>4)*8+j
//       p2 is channel-last: k_phys = px*128+c  ->  logical k = c*64+px
// qwfc2: fp32 sign [10][256]
__global__ __launch_bounds__(256) void k_signgen(const float* __restrict__ w1, const float* __restrict__ w2,
                                                 const float* __restrict__ wfc1, const float* __restrict__ wfc2,
                                                 float* __restrict__ qw1t, u16* __restrict__ qw2b,
                                                 u16* __restrict__ qfc1b, float* __restrict__ qwfc2){
  int i = blockIdx.x * 256 + threadIdx.x;
  if (i < 2097152){
    int j = i & 7, lane = (i >> 3) & 63, fid = i >> 9;
    int kstep = fid >> 4, nt = fid & 15;
    int co = nt*16 + (lane & 15);
    int k_phys = kstep*32 + (lane >> 4)*8 + j;
    int px = k_phys >> 7, c = k_phys & 127;
    qfc1b[i] = sgn_bf(wfc1[(size_t)co*8192 + c*64 + px]);
  } else if (i < 2097152 + 73728){
    int i2 = i - 2097152;
    int j = i2 & 7, lane = (i2 >> 3) & 63, fid = i2 >> 9;  // 0..143
    int s = fid >> 4, ks = (fid >> 3) & 1, nt = fid & 7;
    int co = (lane & 15)*8 + nt;
    int c = ks*32 + (lane >> 4)*8 + j;
    qw2b[i2] = sgn_bf(w2[((size_t)co*64 + c)*9 + s]);
  } else if (i < 2097152 + 73728 + 1728){
    int i3 = i - (2097152 + 73728);
    int co = i3 / 27, k = i3 % 27;
    qw1t[k*64 + co] = sgnf(w1[i3]);
  } else if (i < 2097152 + 73728 + 1728 + 2560){
    int i4 = i - (2097152 + 73728 + 1728);
    qwfc2[i4] = sgnf(wfc2[i4]);
  }
}

// ---------- conv1: x[1024,3,32,32] fp32 -> h1t[1024, 1024px, 64c] bf16 channel-last ----------
__global__ __launch_bounds__(256) void k_conv1(const float* __restrict__ x, const float* __restrict__ qw1t,
                                               const float* __restrict__ absum, u16* __restrict__ h1t){
  __shared__ float xs[3*34*36]; // [ci][y 0..33][x 0..35], data y=1..32, x=2..33
  int n = blockIdx.x, t = threadIdx.x;
  for (int i = t; i < 3672; i += 256) xs[i] = 0.f;
  __syncthreads();
  const float4* xg = (const float4*)(x + (size_t)n * 3072);
  for (int i = t; i < 768; i += 256){
    float4 v = xg[i];
    int ci = i >> 8, rem = i & 255, y = rem >> 3, xq = (rem & 7) * 4;
    int base = ci*1224 + (y+1)*36 + 2 + xq;
    xs[base+0] = v.x; xs[base+1] = v.y; xs[base+2] = v.z; xs[base+3] = v.w;
  }
  __syncthreads();
  float alpha = absum[0] * (1.f/1728.f);
  int yy0[4], xx0[4];
  #pragma unroll
  for (int s = 0; s < 4; ++s){ int sp = t + 256*s; yy0[s] = sp >> 5; xx0[s] = sp & 31; }
  for (int cc = 0; cc < 8; ++cc){
    float acc[4][8];
    #pragma unroll
    for (int s = 0; s < 4; ++s)
      #pragma unroll
      for (int r = 0; r < 8; ++r) acc[s][r] = 0.f;
    for (int ci = 0; ci < 3; ++ci){
      #pragma unroll
      for (int dy = 0; dy < 3; ++dy){
        #pragma unroll
        for (int dx = 0; dx < 3; ++dx){
          int k = ci*9 + dy*3 + dx;
          float wv[8];
          #pragma unroll
          for (int r = 0; r < 8; ++r) wv[r] = qw1t[k*64 + cc*8 + r]; // uniform -> s_load
          #pragma unroll
          for (int s = 0; s < 4; ++s){
            float a = xs[ci*1224 + (yy0[s]+dy)*36 + (xx0[s]+dx+1)];
            #pragma unroll
            for (int r = 0; r < 8; ++r) acc[s][r] += a * wv[r];
          }
        }
      }
    }
    #pragma unroll
    for (int s = 0; s < 4; ++s){
      u16x8 pk;
      #pragma unroll
      for (int r = 0; r < 8; ++r) pk[r] = f2bf(acc[s][r] * alpha);
      *(u16x8*)(h1t + ((size_t)n*1024 + t + 256*s)*64 + cc*8) = pk;
    }
  }
}

// ---------- per-channel stats over channel-last h1t[1024][1024][64] ----------
__global__ __launch_bounds__(256) void k_stats_cl(const u16* __restrict__ h1t, float* __restrict__ sum,
                                                  float* __restrict__ sumsq){
  int n = blockIdx.x, t = threadIdx.x;
  int cp = t & 31, chunk = t >> 5;
  const u32* base = (const u32*)h1t + (size_t)n * 32768;
  float s1a = 0.f, s2a = 0.f, s1b = 0.f, s2b = 0.f;
  for (int px = chunk; px < 1024; px += 8){
    u32 v = base[px*32 + cp];
    float a = bf2f((u16)(v & 0xffffu)), b = bf2f((u16)(v >> 16));
    s1a += a; s2a += a*a; s1b += b; s2b += b*b;
  }
  __shared__ float l1[256], l2[256], l3[256], l4[256];
  l1[t] = s1a; l2[t] = s2a; l3[t] = s1b; l4[t] = s2b;
  __syncthreads();
  if (t < 32){
    float a = 0.f, b = 0.f, c = 0.f, d = 0.f;
    #pragma unroll
    for (int k = 0; k < 8; ++k){ a += l1[t+32*k]; b += l2[t+32*k]; c += l3[t+32*k]; d += l4[t+32*k]; }
    atomicAdd(sum + 2*t, a);     atomicAdd(sumsq + 2*t, b);
    atomicAdd(sum + 2*t + 1, c); atomicAdd(sumsq + 2*t + 1, d);
  }
}

// ---------- finalize BN affine params ----------
__global__ void k_fin(const float* __restrict__ sum, const float* __restrict__ sumsq,
                      const float* __restrict__ g, const float* __restrict__ b,
                      float* __restrict__ scale, float* __restrict__ bias, int C, float invc){
  int c = blockIdx.x * blockDim.x + threadIdx.x;
  if (c >= C) return;
  float m = sum[c] * invc;
  float var = sumsq[c] * invc - m*m;
  float sc = g[c] * rsqrtf(var + 1e-5f);
  scale[c] = sc;
  bias[c] = b[c] - m * sc;
}

// ---------- BN+ReLU+pool channel-last: h1t[1024][32x32][64] -> p1t[1024][16x16][64] ----------
// scale>0 (g=1), so max-then-affine == affine-then-max (exact)
__global__ __launch_bounds__(256) void k_pool1t(const u16* __restrict__ h1t, u16* __restrict__ p1t,
                                                const float* __restrict__ sc, const float* __restrict__ bi){
  __shared__ float lsc[64], lbi[64];
  int n = blockIdx.x, t = threadIdx.x;
  if (t < 64) lsc[t] = sc[t];
  else if (t < 128) lbi[t - 64] = bi[t - 64];
  __syncthreads();
  int oy = t >> 4, ox = t & 15;
  const u16* b00 = h1t + ((size_t)n*1024 + oy*64 + ox*2)*64;
  u16x8 ovv[8];
  #pragma unroll
  for (int v = 0; v < 8; ++v){
    u16x8 a0 = *(const u16x8*)(b00 + v*8);
    u16x8 a1 = *(const u16x8*)(b00 + 64 + v*8);
    u16x8 a2 = *(const u16x8*)(b00 + 2048 + v*8);
    u16x8 a3 = *(const u16x8*)(b00 + 2112 + v*8);
    #pragma unroll
    for (int j = 0; j < 8; ++j){
      int c = v*8 + j;
      float m = fmaxf(fmaxf(bf2f(a0[j]), bf2f(a1[j])), fmaxf(bf2f(a2[j]), bf2f(a3[j])));
      ovv[v][j] = f2bf(fmaxf(m * lsc[c] + lbi[c], 0.f));
    }
  }
  u16* dst = p1t + ((size_t)n*256 + t)*64;
  #pragma unroll
  for (int v = 0; v < 8; ++v) *(u16x8*)(dst + v*8) = ovv[v];
}

// ---------- conv2 via MFMA, barrier-free K-loop ----------
// p1t[1024][256px][64c] -> h2t[1024][256px][128co] bf16 (co = l15*8+nt permuted store is
// the IDENTITY in co because qw2b already bakes the permutation). Fused BN2 stats.
// Per block: one image. Wave w: rows y = w*4..w*4+3 (4 mt), all 128 co (8 nt).
__global__ __launch_bounds__(256, 2) void k_conv2m(const u16* __restrict__ p1t, const u16* __restrict__ qw2b,
                                                   const float* __restrict__ absum, u16* __restrict__ h2t,
                                                   float* __restrict__ gs, float* __restrict__ gq){
  __shared__ __align__(16) u16 img[16384];   // 32 KB, XOR-swizzled 16B units
  __shared__ float ls1[128], ls2[128];
  int n = blockIdx.x, t = threadIdx.x;
  if (t < 128){ ls1[t] = 0.f; ls2[t] = 0.f; }
  const u16* src = p1t + (size_t)n * 16384;
  #pragma unroll
  for (int i = 0; i < 8; ++i){
    int id = i*256 + t;            // = px*8 + unit
    int px = id >> 3, unit = id & 7;
    int su = unit ^ (px & 7);
    *(u16x8*)(img + px*64 + su*8) = *(const u16x8*)(src + id*8);
  }
  __syncthreads();
  int w = t >> 6, lane = t & 63, l15 = lane & 15, q = lane >> 4;
  const s8v* bp = (const s8v*)qw2b;
  f4v acc[4][8];
  #pragma unroll
  for (int a = 0; a < 4; ++a)
    #pragma unroll
    for (int b = 0; b < 8; ++b) acc[a][b] = (f4v)(0.0f);
  for (int dy = 0; dy < 3; ++dy){
    for (int dx = 0; dx < 3; ++dx){
      int s = dy*3 + dx;
      int xv = l15 + dx - 1;
      bool vx = (xv >= 0) && (xv < 16);
      int xc = min(max(xv, 0), 15);
      #pragma unroll
      for (int ks = 0; ks < 2; ++ks){
        s8v bf[8];
        #pragma unroll
        for (int nt = 0; nt < 8; ++nt) bf[nt] = bp[((s*2 + ks)*8 + nt)*64 + lane];
        #pragma unroll
        for (int mt = 0; mt < 4; ++mt){
          int yv = w*4 + mt + dy - 1;
          if (yv < 0 || yv > 15) continue;
          int px = yv*16 + xc;
          int su = (ks*4 + q) ^ (px & 7);
          s8v av = *(const s8v*)(img + px*64 + su*8);
          if (!vx) av = (s8v)(short)0;
          #pragma unroll
          for (int nt = 0; nt < 8; ++nt)
            acc[mt][nt] = __builtin_amdgcn_mfma_f32_16x16x32_bf16(av, bf[nt], acc[mt][nt], 0, 0, 0);
        }
      }
    }
  }
  float alpha = absum[1] * (1.f/73728.f);
  float s1v[8], s2v[8];
  #pragma unroll
  for (int nt = 0; nt < 8; ++nt){ s1v[nt] = 0.f; s2v[nt] = 0.f; }
  #pragma unroll
  for (int mt = 0; mt < 4; ++mt){
    int y = w*4 + mt;
    #pragma unroll
    for (int r = 0; r < 4; ++r){
      int px = y*16 + q*4 + r;
      u16x8 pk;
      #pragma unroll
      for (int nt = 0; nt < 8; ++nt){
        float v = acc[mt][nt][r] * alpha;
        s1v[nt] += v; s2v[nt] += v*v;
        pk[nt] = f2bf(v);
      }
      *(u16x8*)(h2t + ((size_t)n*256 + px)*128 + l15*8) = pk;
    }
  }
  // reduce over q-groups (lanes sharing l15): xor 16, 32
  #pragma unroll
  for (int nt = 0; nt < 8; ++nt){
    s1v[nt] += __shfl_xor(s1v[nt], 16); s1v[nt] += __shfl_xor(s1v[nt], 32);
    s2v[nt] += __shfl_xor(s2v[nt], 16); s2v[nt] += __shfl_xor(s2v[nt], 32);
  }
  if (q == 0){
    #pragma unroll
    for (int nt = 0; nt < 8; ++nt){
      atomicAdd(&ls1[l15*8 + nt], s1v[nt]);
      atomicAdd(&ls2[l15*8 + nt], s2v[nt]);
    }
  }
  __syncthreads();
  if (t < 128){ atomicAdd(gs + t, ls1[t]); atomicAdd(gq + t, ls2[t]); }
}

// ---------- BN2+ReLU+pool channel-last: h2t[1024][16x16][128] -> p2[1024][8x8][128] ----------
__global__ __launch_bounds__(256) void k_pool2t(const u16* __restrict__ h2t, u16* __restrict__ p2,
                                                const float* __restrict__ sc, const float* __restrict__ bi){
  __shared__ float lsc[128], lbi[128];
  int n = blockIdx.x, t = threadIdx.x;
  if (t < 128) lsc[t] = sc[t];
  else lbi[t - 128] = bi[t - 128];
  __syncthreads();
  int opx = t >> 2, cq = t & 3;
  int oy = opx >> 3, ox = opx & 7;
  const u16* base = h2t + (size_t)n*32768 + ((oy*2)*16 + ox*2)*128 + cq*32;
  u16* dst = p2 + (size_t)n*8192 + opx*128 + cq*32;
  #pragma unroll
  for (int v = 0; v < 4; ++v){
    u16x8 a0 = *(const u16x8*)(base + v*8);
    u16x8 a1 = *(const u16x8*)(base + 128 + v*8);
    u16x8 a2 = *(const u16x8*)(base + 2048 + v*8);
    u16x8 a3 = *(const u16x8*)(base + 2176 + v*8);
    u16x8 o;
    #pragma unroll
    for (int j = 0; j < 8; ++j){
      int c = cq*32 + v*8 + j;
      float m = fmaxf(fmaxf(bf2f(a0[j]), bf2f(a1[j])), fmaxf(bf2f(a2[j]), bf2f(a3[j])));
      o[j] = f2bf(fmaxf(m * lsc[c] + lbi[c], 0.f));
    }
    *(u16x8*)(dst + v*8) = o;
  }
}

// ---------- fc1 via MFMA, k-split 16: p2[1024][8192] x signs -> h3p[16][1024][256] ----------
__global__ __launch_bounds__(256) void k_fc1m(const u16* __restrict__ p2, const u16* __restrict__ qfc1b,
                                              const float* __restrict__ absum, float* __restrict__ h3p){
  int t = threadIdx.x;
  int bm = blockIdx.x, bn = blockIdx.y, kb = blockIdx.z;
  int w = t >> 6, lane = t & 63, l15 = lane & 15, q = lane >> 4;
  int rowbase = bm*128 + (w >> 1)*64;
  int ntb = bn*8 + (w & 1)*4;
  const s8v* bp = (const s8v*)qfc1b;
  f4v acc[4][4];
  #pragma unroll
  for (int a = 0; a < 4; ++a)
    #pragma unroll
    for (int b = 0; b < 4; ++b) acc[a][b] = (f4v)(0.0f);
  #pragma unroll 2
  for (int ks = 0; ks < 16; ++ks){
    int kst = kb*16 + ks;
    s8v bf[4], af[4];
    #pragma unroll
    for (int nt = 0; nt < 4; ++nt) bf[nt] = bp[(kst*16 + ntb + nt)*64 + lane];
    #pragma unroll
    for (int mt = 0; mt < 4; ++mt)
      af[mt] = *(const s8v*)(p2 + (size_t)(rowbase + mt*16 + l15)*8192 + kst*32 + q*8);
    #pragma unroll
    for (int mt = 0; mt < 4; ++mt)
      #pragma unroll
      for (int nt = 0; nt < 4; ++nt)
        acc[mt][nt] = __builtin_amdgcn_mfma_f32_16x16x32_bf16(af[mt], bf[nt], acc[mt][nt], 0, 0, 0);
  }
  float alpha = absum[2] * (1.f/2097152.f);
  float* dst = h3p + (size_t)kb * 262144;
  #pragma unroll
  for (int mt = 0; mt < 4; ++mt)
    #pragma unroll
    for (int nt = 0; nt < 4; ++nt){
      int col = (ntb + nt)*16 + l15;
      #pragma unroll
      for (int r = 0; r < 4; ++r)
        dst[(size_t)(rowbase + mt*16 + q*4 + r)*256 + col] = acc[mt][nt][r] * alpha;
    }
}

// ---------- reduce k-split slabs + BN3 stats + materialize h3 ----------
__global__ __launch_bounds__(256) void k_fin3f(const float* __restrict__ h3p, float* __restrict__ h3,
                                               float* __restrict__ s3, float* __restrict__ q3){
  int jb = blockIdx.x, ns = blockIdx.y, t = threadIdx.x;
  int jj = t & 31, nn = t >> 5;
  int j = jb*32 + jj;
  float s1 = 0.f, s2 = 0.f;
  for (int i = nn; i < 128; i += 8){
    int n = i*8 + ns;
    float v = 0.f;
    #pragma unroll 8
    for (int kb = 0; kb < 16; ++kb) v += h3p[(size_t)kb*262144 + n*256 + j];
    h3[n*256 + j] = v;
    s1 += v; s2 += v*v;
  }
  __shared__ float l1[256], l2[256];
  l1[t] = s1; l2[t] = s2;
  __syncthreads();
  if (t < 32){
    float a = 0.f, b = 0.f;
    #pragma unroll
    for (int k = 0; k < 8; ++k){ a += l1[t+32*k]; b += l2[t+32*k]; }
    atomicAdd(s3 + jb*32 + t, a); atomicAdd(q3 + jb*32 + t, b);
  }
}

// ---------- fc2: relu(bn3(h3)) @ sign(wfc2)^T -> out[1024,10] fp32 ----------
__global__ __launch_bounds__(64) void k_fc2(const float* __restrict__ h3, const float* __restrict__ qwfc2,
                                            const float* __restrict__ absum, const float* __restrict__ scale,
                                            const float* __restrict__ bias, float* __restrict__ out){
  int n = blockIdx.x, lane = threadIdx.x;
  float a[4];
  #pragma unroll
  for (int i = 0; i < 4; ++i){
    int j = lane + 64*i;
    float v = h3[(size_t)n*256 + j] * scale[j] + bias[j];
    a[i] = fmaxf(v, 0.f);
  }
  float alpha = absum[3] * (1.f/2560.f);
  #pragma unroll
  for (int k = 0; k < 10; ++k){
    float p = 0.f;
    #pragma unroll
    for (int i = 0; i < 4; ++i) p += a[i] * qwfc2[k*256 + lane + 64*i];
    #pragma unroll
    for (int off = 32; off > 0; off >>= 1) p += __shfl_down(p, off);
    if (lane == 0) out[n*10 + k] = p * alpha;
  }
}

extern "C" void kernel_launch(void* const* d_in, const int* in_sizes, int n_in,
                              void* d_out, int out_size, void* d_ws, size_t ws_size,
                              hipStream_t stream){
  (void)in_sizes; (void)n_in; (void)out_size; (void)ws_size;
  const float* x    = (const float*)d_in[0];
  const float* w1   = (const float*)d_in[1];
  const float* g1   = (const float*)d_in[2];
  const float* b1   = (const float*)d_in[3];
  const float* w2   = (const float*)d_in[4];
  const float* g2   = (const float*)d_in[5];
  const float* b2   = (const float*)d_in[6];
  const float* wfc1 = (const float*)d_in[7];
  const float* g3   = (const float*)d_in[8];
  const float* b3   = (const float*)d_in[9];
  const float* wfc2 = (const float*)d_in[10];
  float* out = (float*)d_out;

  float* wsf = (float*)d_ws;
  char*  wsb = (char*)d_ws;
  float* absum = wsf;
  float* s1 = wsf + 16;   float* q1 = wsf + 80;
  float* s2 = wsf + 144;  float* q2 = wsf + 272;
  float* s3 = wsf + 1024; float* q3 = wsf + 1280;
  float* sc1 = wsf + 1536; float* bi1 = wsf + 1600;
  float* sc2 = wsf + 1664; float* bi2 = wsf + 1792;
  float* sc3 = wsf + 2048; float* bi3 = wsf + 2304;
  float* qw1t  = wsf + 4096;                         // 1728 fp32
  u16*   qw2b  = (u16*)(wsb + (64u << 10));          // 144 KB bf16 B-frags
  float* qwfc2 = (float*)(wsb + (256u << 10));       // 10 KB fp32
  float* h3    = (float*)(wsb + (1ull << 20));       // 1 MB fp32 [1024][256]
  u16*   qfc1b = (u16*)(wsb + (2ull << 20));         // 4 MB bf16 B-frags
  u16*   p1t   = (u16*)(wsb + (8ull << 20) + 4096);  // 32 MB bf16 [1024][256][64]
  u16*   h1t   = (u16*)(wsb + (48ull << 20));        // 128 MB bf16 [1024][1024][64]
  u16*   h2t   = h1t;                                // 64 MB alias (h1t dead after pool1t)
  u16*   p2    = (u16*)(wsb + (112ull << 20));       // 16 MB bf16 [1024][8192] (channel-last k)
  float* h3p   = (float*)(wsb + (48ull << 20));      // 16 MB fp32 [16][1024][256] (h2t dead)

  k_zero<<<10, 256, 0, stream>>>(wsf, 2560);
  k_absum<<<98, 256, 0, stream>>>(w1, w2, wfc1, wfc2, absum);
  k_signgen<<<8498, 256, 0, stream>>>(w1, w2, wfc1, wfc2, qw1t, qw2b, qfc1b, qwfc2);
  k_conv1<<<1024, 256, 0, stream>>>(x, qw1t, absum, h1t);
  k_stats_cl<<<1024, 256, 0, stream>>>(h1t, s1, q1);
  k_fin<<<1, 64, 0, stream>>>(s1, q1, g1, b1, sc1, bi1, 64, 1.f/1048576.f);
  k_pool1t<<<1024, 256, 0, stream>>>(h1t, p1t, sc1, bi1);
  k_conv2m<<<1024, 256, 0, stream>>>(p1t, qw2b, absum, h2t, s2, q2);
  k_fin<<<1, 128, 0, stream>>>(s2, q2, g2, b2, sc2, bi2, 128, 1.f/262144.f);
  k_pool2t<<<1024, 256, 0, stream>>>(h2t, p2, sc2, bi2);
  k_fc1m<<<dim3(8, 2, 16), 256, 0, stream>>>(p2, qfc1b, absum, h3p);
  k_fin3f<<<dim3(8, 8), 256, 0, stream>>>(h3p, h3, s3, q3);
  k_fin<<<1, 256, 0, stream>>>(s3, q3, g3, b3, sc3, bi3, 256, 1.f/1024.f);
  k_fc2<<<1024, 64, 0, stream>>>(h3, qwfc2, absum, sc3, bi3, out);
}